// Round 3
// baseline (162.828 us; speedup 1.0000x reference)
//
#include <hip/hip_runtime.h>
#include <hip/hip_bf16.h>
#include <stdint.h>

#define B_ 4
#define T_ 64
#define L_ 4096
#define D_ 4096

using bf8   = __attribute__((ext_vector_type(8))) short;   // 8 bf16 (4 VGPRs)
using f32x4 = __attribute__((ext_vector_type(4))) float;   // MFMA accumulator

// round-to-nearest-even fp32 -> bf16 (bit pattern in ushort)
__device__ __forceinline__ unsigned short f2bf(float f) {
    union { float f; unsigned int u; } v;
    v.f = f;
    unsigned int r = v.u + 0x7fffu + ((v.u >> 16) & 1u);
    return (unsigned short)(r >> 16);
}

// XOR swizzle on 16B chunks within a 256B LDS row; same fn on write & read.
__device__ __forceinline__ int swz16(int row, int byteoff) {
    return byteoff ^ (((row ^ (row >> 3)) & 7) << 4);
}

// MFMA fragment read from a [rows][128] bf16 tile (256B row stride).
// kk = which 32-wide K quarter (0..3). Lane layout for mfma_f32_16x16x32_bf16:
// row/col = lane&15, k = (lane>>4)*8 + j.
__device__ __forceinline__ bf8 read_frag(const unsigned short* lds, int row, int kk, int lane) {
    int byte = kk * 64 + ((lane >> 4) << 4);
    int off  = row * 256 + swz16(row, byte);
    return *reinterpret_cast<const bf8*>(reinterpret_cast<const char*>(lds) + off);
}

// ---------------- Kernel 0: Q fp32 -> bf16 once (shared by all k_scores blocks) ----------------
__global__ __launch_bounds__(256) void k_qprep(const float* __restrict__ Q,
                                               unsigned short* __restrict__ Qbf) {
    int i = blockIdx.x * 256 + threadIdx.x;          // T*D/4 = 65536 float4s
    float4 f = reinterpret_cast<const float4*>(Q)[i];
    ushort4 u;
    u.x = f2bf(f.x); u.y = f2bf(f.y); u.z = f2bf(f.z); u.w = f2bf(f.w);
    reinterpret_cast<ushort4*>(Qbf)[i] = u;
}

// ---------------- Kernel 1: scores[b,t,l] = (Q[t,:] . mask[b,l,:]) / 64 ----------------
// grid (L/64, B) = 256 blocks, 1/CU. Tile M=64(T) x N=64(l), K-step 128.
// 32 KB of mask-HBM per iteration -> delivery time (~2900 cyc) >> latency (~900) -> drain amortized.
__global__ __launch_bounds__(256, 1) void k_scores(
    const float* __restrict__ mask, const unsigned short* __restrict__ Qbf,
    float* __restrict__ scores) {
    __shared__ unsigned short lA[2][64 * 128];   // Q tile   [t][k]
    __shared__ unsigned short lB[2][64 * 128];   // mask tile[l][k]
    const int tid  = threadIdx.x;
    const int lane = tid & 63;
    const int wave = tid >> 6;
    const int wm = wave >> 1, wn = wave & 1;     // 2x2 waves, 32x32 out each
    const int b  = blockIdx.y;
    const int l0 = blockIdx.x * 64;
    const float* __restrict__ Mb = mask + (size_t)b * L_ * D_;

    f32x4 acc[2][2] = {};
    uint4  ra[4];    // Q slab:   64 x 128 bf16 = 16 KB -> 4 uint4/thread
    float4 rb[8];    // mask slab:64 x 128 f32  = 32 KB -> 8 float4/thread

    auto loadTiles = [&](int k0) {
#pragma unroll
        for (int s = 0; s < 4; ++s) {
            int slot = tid + s * 256;
            int r = slot >> 4, c = slot & 15;                 // 16 uint4 per row
            ra[s] = *reinterpret_cast<const uint4*>(Qbf + (size_t)r * D_ + k0 + c * 8);
        }
#pragma unroll
        for (int s = 0; s < 8; ++s) {
            int slot = tid + s * 256;
            int r = slot >> 5, c = slot & 31;                 // 32 float4 per row
            rb[s] = *reinterpret_cast<const float4*>(Mb + (size_t)(l0 + r) * D_ + k0 + c * 4);
        }
    };
    auto writeTiles = [&](int buf) {
#pragma unroll
        for (int s = 0; s < 4; ++s) {
            int slot = tid + s * 256;
            int r = slot >> 4, c = slot & 15;
            int off = r * 256 + swz16(r, c * 16);
            *reinterpret_cast<uint4*>(reinterpret_cast<char*>(lA[buf]) + off) = ra[s];
        }
#pragma unroll
        for (int s = 0; s < 8; ++s) {
            int slot = tid + s * 256;
            int r = slot >> 5, c = slot & 31;
            int off = r * 256 + swz16(r, c * 8);
            ushort4 u;
            u.x = f2bf(rb[s].x); u.y = f2bf(rb[s].y); u.z = f2bf(rb[s].z); u.w = f2bf(rb[s].w);
            *reinterpret_cast<ushort4*>(reinterpret_cast<char*>(lB[buf]) + off) = u;
        }
    };

    loadTiles(0);
    writeTiles(0);
    __syncthreads();
    const int NT = D_ / 128;                     // 32 iterations
    for (int kt = 0; kt < NT; ++kt) {
        int cur = kt & 1;
        if (kt + 1 < NT) loadTiles((kt + 1) * 128);   // issue early: full compute+delivery window
#pragma unroll
        for (int kk = 0; kk < 4; ++kk) {
            bf8 a0 = read_frag(lA[cur], wm * 32 +      (lane & 15), kk, lane);
            bf8 a1 = read_frag(lA[cur], wm * 32 + 16 + (lane & 15), kk, lane);
            bf8 b0 = read_frag(lB[cur], wn * 32 +      (lane & 15), kk, lane);
            bf8 b1 = read_frag(lB[cur], wn * 32 + 16 + (lane & 15), kk, lane);
            acc[0][0] = __builtin_amdgcn_mfma_f32_16x16x32_bf16(a0, b0, acc[0][0], 0, 0, 0);
            acc[0][1] = __builtin_amdgcn_mfma_f32_16x16x32_bf16(a0, b1, acc[0][1], 0, 0, 0);
            acc[1][0] = __builtin_amdgcn_mfma_f32_16x16x32_bf16(a1, b0, acc[1][0], 0, 0, 0);
            acc[1][1] = __builtin_amdgcn_mfma_f32_16x16x32_bf16(a1, b1, acc[1][1], 0, 0, 0);
        }
        if (kt + 1 < NT) writeTiles(cur ^ 1);
        __syncthreads();
    }

    // C/D layout: col = lane&15, row = (lane>>4)*4 + reg  (m89-verified)
    const int rgrp = (lane >> 4) * 4;
    const int cidx = lane & 15;
#pragma unroll
    for (int mi = 0; mi < 2; ++mi)
#pragma unroll
        for (int nj = 0; nj < 2; ++nj)
#pragma unroll
            for (int r = 0; r < 4; ++r) {
                int t = wm * 32 + mi * 16 + rgrp + r;
                int l = l0 + wn * 32 + nj * 16 + cidx;
                scores[((size_t)b * T_ + t) * L_ + l] = acc[mi][nj][r] * 0.015625f; // 1/sqrt(4096)
            }
}

// ---------------- Kernel 2: masked softmax over L, fp32 scores -> bf16 attn ----------------
__global__ __launch_bounds__(256, 4) void k_softmax(
    const float* __restrict__ scores, const int* __restrict__ am,
    unsigned short* __restrict__ attn) {
    const int row  = blockIdx.x;                 // b*T + t
    const int tid  = threadIdx.x;
    const int lane = tid & 63;
    const int wave = tid >> 6;
    const float* __restrict__ s = scores + (size_t)row * L_;
    const int*   __restrict__ m = am     + (size_t)row * L_;
    __shared__ float redmax[4], redsum[4];

    float v[16];
#pragma unroll
    for (int j = 0; j < 4; ++j) {
        float4 f = *(reinterpret_cast<const float4*>(s) + tid + j * 256);
        int4   q = *(reinterpret_cast<const int4*>(m)   + tid + j * 256);
        v[j * 4 + 0] = q.x ? -1.0e9f : f.x;
        v[j * 4 + 1] = q.y ? -1.0e9f : f.y;
        v[j * 4 + 2] = q.z ? -1.0e9f : f.z;
        v[j * 4 + 3] = q.w ? -1.0e9f : f.w;
    }
    float mx = -3.0e38f;
#pragma unroll
    for (int i = 0; i < 16; ++i) mx = fmaxf(mx, v[i]);
#pragma unroll
    for (int off = 32; off; off >>= 1) mx = fmaxf(mx, __shfl_xor(mx, off, 64));
    if (lane == 0) redmax[wave] = mx;
    __syncthreads();
    mx = fmaxf(fmaxf(redmax[0], redmax[1]), fmaxf(redmax[2], redmax[3]));

    float z = 0.f;
#pragma unroll
    for (int i = 0; i < 16; ++i) {
        v[i] = exp2f((v[i] - mx) * 1.4426950408889634f);
        z += v[i];
    }
#pragma unroll
    for (int off = 32; off; off >>= 1) z += __shfl_xor(z, off, 64);
    if (lane == 0) redsum[wave] = z;
    __syncthreads();
    z = (redsum[0] + redsum[1]) + (redsum[2] + redsum[3]);
    float inv = 1.0f / z;

    unsigned short* __restrict__ arow = attn + (size_t)row * L_;
#pragma unroll
    for (int j = 0; j < 4; ++j) {
        ushort4 u;
        u.x = f2bf(v[j * 4 + 0] * inv);
        u.y = f2bf(v[j * 4 + 1] * inv);
        u.z = f2bf(v[j * 4 + 2] * inv);
        u.w = f2bf(v[j * 4 + 3] * inv);
        *(reinterpret_cast<ushort4*>(arow) + tid + j * 256) = u;
    }
}

// ---------------- Kernel 3: context[b,t,d] = sum_l attn[b,t,l] * mask[b,l,d] ----------------
// grid (D/64, B) = 256 blocks, 1/CU. Tile M=64(T) x N=64(d), K(=l)-step 128.
// B-tile (mask) staged TRANSPOSED into LDS as [d][l] bf16.
__global__ __launch_bounds__(256, 1) void k_context(
    const float* __restrict__ mask, const unsigned short* __restrict__ attn,
    float* __restrict__ out) {
    __shared__ unsigned short lA[2][64 * 128];   // attn [t][l]
    __shared__ unsigned short lB[2][64 * 128];   // mask [d][l] (transposed)
    const int tid  = threadIdx.x;
    const int lane = tid & 63;
    const int wave = tid >> 6;
    const int wm = wave >> 1, wn = wave & 1;
    const int b  = blockIdx.y;
    const int d0 = blockIdx.x * 64;
    const float*          __restrict__ Mb = mask + (size_t)b * L_ * D_;
    const unsigned short* __restrict__ Ab = attn + (size_t)b * T_ * L_;

    f32x4 acc[2][2] = {};
    uint4  ra[4];    // attn slab: 64 t x 128 l bf16 = 16 KB
    float4 rb[8];    // mask slab: 128 l x 64 d f32  = 32 KB

    auto loadTiles = [&](int k0) {
#pragma unroll
        for (int s = 0; s < 4; ++s) {
            int slot = tid + s * 256;
            int r = slot >> 4, c = slot & 15;                 // 16 uint4 per t-row
            ra[s] = *reinterpret_cast<const uint4*>(Ab + (size_t)r * L_ + k0 + c * 8);
        }
#pragma unroll
        for (int s = 0; s < 8; ++s) {
            int slot = tid + s * 256;
            int kl = slot >> 4, c = slot & 15;                // 16 float4 per l-row
            rb[s] = *reinterpret_cast<const float4*>(Mb + (size_t)(k0 + kl) * D_ + d0 + c * 4);
        }
    };
    auto writeTiles = [&](int buf) {
#pragma unroll
        for (int s = 0; s < 4; ++s) {
            int slot = tid + s * 256;
            int r = slot >> 4, c = slot & 15;
            int off = r * 256 + swz16(r, c * 16);
            *reinterpret_cast<uint4*>(reinterpret_cast<char*>(lA[buf]) + off) = ra[s];
        }
#pragma unroll
        for (int s = 0; s < 8; ++s) {
            int slot = tid + s * 256;
            int kl = slot >> 4, c = slot & 15;
            float fv[4] = { rb[s].x, rb[s].y, rb[s].z, rb[s].w };
#pragma unroll
            for (int i = 0; i < 4; ++i) {
                int d = c * 4 + i;
                int off = d * 256 + swz16(d, kl * 2);
                *reinterpret_cast<unsigned short*>(reinterpret_cast<char*>(lB[buf]) + off) = f2bf(fv[i]);
            }
        }
    };

    loadTiles(0);
    writeTiles(0);
    __syncthreads();
    const int NT = L_ / 128;                     // 32 iterations
    for (int kt = 0; kt < NT; ++kt) {
        int cur = kt & 1;
        if (kt + 1 < NT) loadTiles((kt + 1) * 128);
#pragma unroll
        for (int kk = 0; kk < 4; ++kk) {
            bf8 a0 = read_frag(lA[cur], wm * 32 +      (lane & 15), kk, lane);
            bf8 a1 = read_frag(lA[cur], wm * 32 + 16 + (lane & 15), kk, lane);
            bf8 b0 = read_frag(lB[cur], wn * 32 +      (lane & 15), kk, lane);
            bf8 b1 = read_frag(lB[cur], wn * 32 + 16 + (lane & 15), kk, lane);
            acc[0][0] = __builtin_amdgcn_mfma_f32_16x16x32_bf16(a0, b0, acc[0][0], 0, 0, 0);
            acc[0][1] = __builtin_amdgcn_mfma_f32_16x16x32_bf16(a0, b1, acc[0][1], 0, 0, 0);
            acc[1][0] = __builtin_amdgcn_mfma_f32_16x16x32_bf16(a1, b0, acc[1][0], 0, 0, 0);
            acc[1][1] = __builtin_amdgcn_mfma_f32_16x16x32_bf16(a1, b1, acc[1][1], 0, 0, 0);
        }
        if (kt + 1 < NT) writeTiles(cur ^ 1);
        __syncthreads();
    }

    const int rgrp = (lane >> 4) * 4;
    const int cidx = lane & 15;
#pragma unroll
    for (int mi = 0; mi < 2; ++mi)
#pragma unroll
        for (int nj = 0; nj < 2; ++nj)
#pragma unroll
            for (int r = 0; r < 4; ++r) {
                int t = wm * 32 + mi * 16 + rgrp + r;
                int d = d0 + wn * 32 + nj * 16 + cidx;
                out[((size_t)b * T_ + t) * D_ + d] = acc[mi][nj][r];
            }
}

extern "C" void kernel_launch(void* const* d_in, const int* in_sizes, int n_in,
                              void* d_out, int out_size, void* d_ws, size_t ws_size,
                              hipStream_t stream) {
    const float* mask = (const float*)d_in[0];        // [B, L, D] fp32
    const float* Q    = (const float*)d_in[1];        // [1, T, D] fp32
    const int*   am   = (const int*)d_in[2];          // [B, T, L] int (bool)
    float* out = (float*)d_out;                       // [B, T, D] fp32

    unsigned short* attn = (unsigned short*)d_ws;                       // 2 MB bf16
    unsigned short* Qbf  = (unsigned short*)((char*)d_ws + (size_t)B_ * T_ * L_ * 2); // 512 KB

    // Pass 0: Q -> bf16 once
    k_qprep<<<dim3(T_ * D_ / 4 / 256), 256, 0, stream>>>(Q, Qbf);
    // Pass 1: raw scaled scores into d_out
    k_scores<<<dim3(L_ / 64, B_), 256, 0, stream>>>(mask, Qbf, out);
    // Pass 2: masked softmax, bf16 attn weights into workspace
    k_softmax<<<dim3(B_ * T_), 256, 0, stream>>>(out, am, attn);
    // Pass 3: context = attn @ mask, overwrite d_out
    k_context<<<dim3(D_ / 64, B_), 256, 0, stream>>>(mask, attn, out);
}

// Round 4
// 144.101 us; speedup vs baseline: 1.1300x; 1.1300x over previous
//
#include <hip/hip_runtime.h>
#include <hip/hip_bf16.h>
#include <stdint.h>

#define B_ 4
#define T_ 64
#define L_ 4096
#define D_ 4096

using bf8   = __attribute__((ext_vector_type(8))) short;   // 8 bf16 (4 VGPRs)
using f32x4 = __attribute__((ext_vector_type(4))) float;   // MFMA accumulator

// round-to-nearest-even fp32 -> bf16 (bit pattern in ushort)
__device__ __forceinline__ unsigned short f2bf(float f) {
    union { float f; unsigned int u; } v;
    v.f = f;
    unsigned int r = v.u + 0x7fffu + ((v.u >> 16) & 1u);
    return (unsigned short)(r >> 16);
}
__device__ __forceinline__ unsigned int pack2(float lo, float hi) {
    return (unsigned int)f2bf(lo) | ((unsigned int)f2bf(hi) << 16);
}

// bf16 tile: 64 elems/row = 128 B = 8 chunks of 16 B. Swizzle: chunk ^= row&7.
// 128 B row stride = exactly one bank period, so without swizzle all rows alias.
__device__ __forceinline__ int tileOff(int row, int chunk) {
    return row * 128 + ((chunk ^ (row & 7)) << 4);
}

// MFMA fragment read. Logical: row, k-bytes = kk*64 + (lane>>4)*16 -> chunk = kk*4 + (lane>>4).
__device__ __forceinline__ bf8 fragRead(const unsigned short* lds, int row, int kk, int lane) {
    return *reinterpret_cast<const bf8*>(
        reinterpret_cast<const char*>(lds) + tileOff(row, kk * 4 + (lane >> 4)));
}

// Raw barrier that does NOT drain vmcnt (keeps prefetch loads in flight).
__device__ __forceinline__ void pipe_barrier() {
    asm volatile("s_waitcnt lgkmcnt(0)" ::: "memory");
    __builtin_amdgcn_sched_barrier(0);
    __builtin_amdgcn_s_barrier();
    __builtin_amdgcn_sched_barrier(0);
}

// ---------------- Kernel 0: Q fp32 -> bf16 once ----------------
__global__ __launch_bounds__(256) void k_qprep(const float* __restrict__ Q,
                                               unsigned short* __restrict__ Qbf) {
    int i = blockIdx.x * 256 + threadIdx.x;          // T*D/4 = 65536 float4s
    float4 f = reinterpret_cast<const float4*>(Q)[i];
    ushort4 u;
    u.x = f2bf(f.x); u.y = f2bf(f.y); u.z = f2bf(f.z); u.w = f2bf(f.w);
    reinterpret_cast<ushort4*>(Qbf)[i] = u;
}

// ==================== Kernel 1: scores = Q . mask^T / 64 ====================
// grid (L/64, B) = 256 blocks. Tile 64(T) x 64(l), K-step 64.
// 2 reg-sets + 2 LDS buffers; loads for tile kt+2 issued before tile kt+1 is
// committed, raw barrier keeps them in flight -> HBM pipe never drains.

struct SRegs { uint4 q[2]; float4 m[4]; };

__device__ __forceinline__ void s_issue(SRegs& R, const unsigned short* Qb,
                                        const float* Mb, int l0, int k0, int tid) {
    const int r  = tid >> 2;
    const int cq = (tid & 3) * 2;
#pragma unroll
    for (int s = 0; s < 2; ++s)
        R.q[s] = *reinterpret_cast<const uint4*>(Qb + (size_t)r * D_ + k0 + (cq + s) * 8);
    const int cm = (tid & 3) * 4;
#pragma unroll
    for (int s = 0; s < 4; ++s)
        R.m[s] = *reinterpret_cast<const float4*>(Mb + (size_t)(l0 + r) * D_ + k0 + (cm + s) * 4);
}

__device__ __forceinline__ void s_commit(const SRegs& R, unsigned short* lA,
                                         unsigned short* lB, int tid) {
    const int r  = tid >> 2;
    const int cq = (tid & 3) * 2;
#pragma unroll
    for (int s = 0; s < 2; ++s)
        *reinterpret_cast<uint4*>(reinterpret_cast<char*>(lA) + tileOff(r, cq + s)) = R.q[s];
    const int cm = (tid & 3) * 2;
#pragma unroll
    for (int j = 0; j < 2; ++j) {
        uint4 w;
        w.x = pack2(R.m[2 * j].x,     R.m[2 * j].y);
        w.y = pack2(R.m[2 * j].z,     R.m[2 * j].w);
        w.z = pack2(R.m[2 * j + 1].x, R.m[2 * j + 1].y);
        w.w = pack2(R.m[2 * j + 1].z, R.m[2 * j + 1].w);
        *reinterpret_cast<uint4*>(reinterpret_cast<char*>(lB) + tileOff(r, cm + j)) = w;
    }
}

__device__ __forceinline__ void mfma_tile(const unsigned short* lA, const unsigned short* lB,
                                          f32x4 acc[2][2], int wm, int wn, int lane) {
#pragma unroll
    for (int kk = 0; kk < 2; ++kk) {
        bf8 a0 = fragRead(lA, wm * 32 +      (lane & 15), kk, lane);
        bf8 a1 = fragRead(lA, wm * 32 + 16 + (lane & 15), kk, lane);
        bf8 b0 = fragRead(lB, wn * 32 +      (lane & 15), kk, lane);
        bf8 b1 = fragRead(lB, wn * 32 + 16 + (lane & 15), kk, lane);
        acc[0][0] = __builtin_amdgcn_mfma_f32_16x16x32_bf16(a0, b0, acc[0][0], 0, 0, 0);
        acc[0][1] = __builtin_amdgcn_mfma_f32_16x16x32_bf16(a0, b1, acc[0][1], 0, 0, 0);
        acc[1][0] = __builtin_amdgcn_mfma_f32_16x16x32_bf16(a1, b0, acc[1][0], 0, 0, 0);
        acc[1][1] = __builtin_amdgcn_mfma_f32_16x16x32_bf16(a1, b1, acc[1][1], 0, 0, 0);
    }
}

__global__ __launch_bounds__(256, 1) void k_scores(
    const float* __restrict__ mask, const unsigned short* __restrict__ Qbf,
    float* __restrict__ scores) {
    __shared__ unsigned short lA[2][64 * 64];
    __shared__ unsigned short lB[2][64 * 64];
    const int tid  = threadIdx.x;
    const int lane = tid & 63;
    const int wave = tid >> 6;
    const int wm = wave >> 1, wn = wave & 1;
    const int b  = blockIdx.y;
    const int l0 = blockIdx.x * 64;
    const float* __restrict__ Mb = mask + (size_t)b * L_ * D_;

    f32x4 acc[2][2] = {};
    SRegs S0, S1;
    const int NT = D_ / 64;                       // 64, even

    s_issue(S0, Qbf, Mb, l0, 0, tid);
    s_issue(S1, Qbf, Mb, l0, 64, tid);
    s_commit(S0, lA[0], lB[0], tid);              // auto-waits S0's 6 loads (vmcnt(6))
    pipe_barrier();

    for (int kt = 0; kt < NT; kt += 2) {
        // sub-iter A: consume tile kt (LDS0), commit tile kt+1 (S1 -> LDS1), prefetch kt+2 -> S0
        int kA = (kt + 2 < NT ? kt + 2 : 0) * 64; // dummy reload of tile 0 in tail (harmless)
        s_issue(S0, Qbf, Mb, l0, kA, tid);
        __builtin_amdgcn_sched_barrier(0);
        mfma_tile(lA[0], lB[0], acc, wm, wn, lane);
        s_commit(S1, lA[1], lB[1], tid);
        pipe_barrier();
        // sub-iter B: consume tile kt+1 (LDS1), commit kt+2 (S0 -> LDS0), prefetch kt+3 -> S1
        int kB = (kt + 3 < NT ? kt + 3 : 0) * 64;
        s_issue(S1, Qbf, Mb, l0, kB, tid);
        __builtin_amdgcn_sched_barrier(0);
        mfma_tile(lA[1], lB[1], acc, wm, wn, lane);
        s_commit(S0, lA[0], lB[0], tid);
        pipe_barrier();
    }

    // C/D layout: col = lane&15, row = (lane>>4)*4 + reg
    const int rgrp = (lane >> 4) * 4;
    const int cidx = lane & 15;
#pragma unroll
    for (int mi = 0; mi < 2; ++mi)
#pragma unroll
        for (int nj = 0; nj < 2; ++nj)
#pragma unroll
            for (int r = 0; r < 4; ++r) {
                int t = wm * 32 + mi * 16 + rgrp + r;
                int l = l0 + wn * 32 + nj * 16 + cidx;
                scores[((size_t)b * T_ + t) * L_ + l] = acc[mi][nj][r] * 0.015625f;
            }
}

// ---------------- Kernel 2: masked softmax over L, fp32 scores -> bf16 attn ----------------
__global__ __launch_bounds__(256, 4) void k_softmax(
    const float* __restrict__ scores, const int* __restrict__ am,
    unsigned short* __restrict__ attn) {
    const int row  = blockIdx.x;                 // b*T + t
    const int tid  = threadIdx.x;
    const int lane = tid & 63;
    const int wave = tid >> 6;
    const float* __restrict__ s = scores + (size_t)row * L_;
    const int*   __restrict__ m = am     + (size_t)row * L_;
    __shared__ float redmax[4], redsum[4];

    float v[16];
#pragma unroll
    for (int j = 0; j < 4; ++j) {
        float4 f = *(reinterpret_cast<const float4*>(s) + tid + j * 256);
        int4   q = *(reinterpret_cast<const int4*>(m)   + tid + j * 256);
        v[j * 4 + 0] = q.x ? -1.0e9f : f.x;
        v[j * 4 + 1] = q.y ? -1.0e9f : f.y;
        v[j * 4 + 2] = q.z ? -1.0e9f : f.z;
        v[j * 4 + 3] = q.w ? -1.0e9f : f.w;
    }
    float mx = -3.0e38f;
#pragma unroll
    for (int i = 0; i < 16; ++i) mx = fmaxf(mx, v[i]);
#pragma unroll
    for (int off = 32; off; off >>= 1) mx = fmaxf(mx, __shfl_xor(mx, off, 64));
    if (lane == 0) redmax[wave] = mx;
    __syncthreads();
    mx = fmaxf(fmaxf(redmax[0], redmax[1]), fmaxf(redmax[2], redmax[3]));

    float z = 0.f;
#pragma unroll
    for (int i = 0; i < 16; ++i) {
        v[i] = exp2f((v[i] - mx) * 1.4426950408889634f);
        z += v[i];
    }
#pragma unroll
    for (int off = 32; off; off >>= 1) z += __shfl_xor(z, off, 64);
    if (lane == 0) redsum[wave] = z;
    __syncthreads();
    z = (redsum[0] + redsum[1]) + (redsum[2] + redsum[3]);
    float inv = 1.0f / z;

    unsigned short* __restrict__ arow = attn + (size_t)row * L_;
#pragma unroll
    for (int j = 0; j < 4; ++j) {
        ushort4 u;
        u.x = f2bf(v[j * 4 + 0] * inv);
        u.y = f2bf(v[j * 4 + 1] * inv);
        u.z = f2bf(v[j * 4 + 2] * inv);
        u.w = f2bf(v[j * 4 + 3] * inv);
        *(reinterpret_cast<ushort4*>(arow) + tid + j * 256) = u;
    }
}

// ==================== Kernel 3: context = attn @ mask ====================
// grid (D/64, B) = 256 blocks. Tile 64(T) x 64(d), K(=l)-step 64.
// mask tile staged TRANSPOSED into LDS as [d][l] bf16 (scalar b16 writes, ~2-way banks).

struct CRegs { uint4 a[2]; float4 m[4]; };

__device__ __forceinline__ void c_issue(CRegs& R, const unsigned short* Ab,
                                        const float* Mb, int d0, int k0, int tid) {
    const int r  = tid >> 2;
    const int ca = (tid & 3) * 2;
#pragma unroll
    for (int s = 0; s < 2; ++s)
        R.a[s] = *reinterpret_cast<const uint4*>(Ab + (size_t)r * L_ + k0 + (ca + s) * 8);
    const int cm = (tid & 3) * 4;
#pragma unroll
    for (int s = 0; s < 4; ++s)
        R.m[s] = *reinterpret_cast<const float4*>(Mb + (size_t)(k0 + r) * D_ + d0 + (cm + s) * 4);
}

__device__ __forceinline__ void c_commit(const CRegs& R, unsigned short* lA,
                                         unsigned short* lB, int tid) {
    const int r  = tid >> 2;                      // t-row (A) / l-row (B source)
    const int ca = (tid & 3) * 2;
#pragma unroll
    for (int s = 0; s < 2; ++s)
        *reinterpret_cast<uint4*>(reinterpret_cast<char*>(lA) + tileOff(r, ca + s)) = R.a[s];
    const int db = (tid & 3) * 16;
#pragma unroll
    for (int s = 0; s < 4; ++s) {
        float fv[4] = { R.m[s].x, R.m[s].y, R.m[s].z, R.m[s].w };
#pragma unroll
        for (int i = 0; i < 4; ++i) {
            int d = db + s * 4 + i;
            // element (row=d, col=l=r): byte-in-row = r*2, chunk = r>>3, swizzled
            int off = d * 128 + ((((r >> 3) ^ (d & 7)) << 4)) + ((r & 7) << 1);
            *reinterpret_cast<unsigned short*>(reinterpret_cast<char*>(lB) + off) = f2bf(fv[i]);
        }
    }
}

__global__ __launch_bounds__(256, 1) void k_context(
    const float* __restrict__ mask, const unsigned short* __restrict__ attn,
    float* __restrict__ out) {
    __shared__ unsigned short lA[2][64 * 64];   // attn [t][l]
    __shared__ unsigned short lB[2][64 * 64];   // mask [d][l] transposed
    const int tid  = threadIdx.x;
    const int lane = tid & 63;
    const int wave = tid >> 6;
    const int wm = wave >> 1, wn = wave & 1;
    const int b  = blockIdx.y;
    const int d0 = blockIdx.x * 64;
    const float*          __restrict__ Mb = mask + (size_t)b * L_ * D_;
    const unsigned short* __restrict__ Ab = attn + (size_t)b * T_ * L_;

    f32x4 acc[2][2] = {};
    CRegs S0, S1;
    const int NT = L_ / 64;                       // 64, even

    c_issue(S0, Ab, Mb, d0, 0, tid);
    c_issue(S1, Ab, Mb, d0, 64, tid);
    c_commit(S0, lA[0], lB[0], tid);
    pipe_barrier();

    for (int kt = 0; kt < NT; kt += 2) {
        int kA = (kt + 2 < NT ? kt + 2 : 0) * 64;
        c_issue(S0, Ab, Mb, d0, kA, tid);
        __builtin_amdgcn_sched_barrier(0);
        mfma_tile(lA[0], lB[0], acc, wm, wn, lane);
        c_commit(S1, lA[1], lB[1], tid);
        pipe_barrier();
        int kB = (kt + 3 < NT ? kt + 3 : 0) * 64;
        c_issue(S1, Ab, Mb, d0, kB, tid);
        __builtin_amdgcn_sched_barrier(0);
        mfma_tile(lA[1], lB[1], acc, wm, wn, lane);
        c_commit(S0, lA[0], lB[0], tid);
        pipe_barrier();
    }

    const int rgrp = (lane >> 4) * 4;
    const int cidx = lane & 15;
#pragma unroll
    for (int mi = 0; mi < 2; ++mi)
#pragma unroll
        for (int nj = 0; nj < 2; ++nj)
#pragma unroll
            for (int r = 0; r < 4; ++r) {
                int t = wm * 32 + mi * 16 + rgrp + r;
                int d = d0 + wn * 32 + nj * 16 + cidx;
                out[((size_t)b * T_ + t) * D_ + d] = acc[mi][nj][r];
            }
}

extern "C" void kernel_launch(void* const* d_in, const int* in_sizes, int n_in,
                              void* d_out, int out_size, void* d_ws, size_t ws_size,
                              hipStream_t stream) {
    const float* mask = (const float*)d_in[0];        // [B, L, D] fp32
    const float* Q    = (const float*)d_in[1];        // [1, T, D] fp32
    const int*   am   = (const int*)d_in[2];          // [B, T, L] int (bool)
    float* out = (float*)d_out;                       // [B, T, D] fp32

    unsigned short* attn = (unsigned short*)d_ws;                                     // 2 MB bf16
    unsigned short* Qbf  = (unsigned short*)((char*)d_ws + (size_t)B_ * T_ * L_ * 2); // 512 KB

    k_qprep<<<dim3(T_ * D_ / 4 / 256), 256, 0, stream>>>(Q, Qbf);
    k_scores<<<dim3(L_ / 64, B_), 256, 0, stream>>>(mask, Qbf, out);
    k_softmax<<<dim3(B_ * T_), 256, 0, stream>>>(out, am, attn);
    k_context<<<dim3(D_ / 64, B_), 256, 0, stream>>>(mask, attn, out);
}

// Round 5
// 140.439 us; speedup vs baseline: 1.1594x; 1.0261x over previous
//
#include <hip/hip_runtime.h>
#include <hip/hip_bf16.h>
#include <stdint.h>

#define B_ 4
#define T_ 64
#define L_ 4096
#define D_ 4096

using bf8   = __attribute__((ext_vector_type(8))) short;   // 8 bf16 (4 VGPRs)
using f32x4 = __attribute__((ext_vector_type(4))) float;   // MFMA accumulator

// round-to-nearest-even fp32 -> bf16 (bit pattern in ushort)
__device__ __forceinline__ unsigned short f2bf(float f) {
    union { float f; unsigned int u; } v;
    v.f = f;
    unsigned int r = v.u + 0x7fffu + ((v.u >> 16) & 1u);
    return (unsigned short)(r >> 16);
}

// XOR swizzle on 16B chunks within a 128B LDS row; same fn on write & read.
// 128B row stride = one full bank period -> unswizzled rows all alias.
__device__ __forceinline__ int swz16(int row, int byteoff) {
    return byteoff ^ (((row ^ (row >> 3)) & 7) << 4);
}

// MFMA fragment read from a [rows][64] bf16 tile (128B row stride).
// kk = which 32-wide K half. Lane layout mfma_f32_16x16x32_bf16: row=lane&15, k=(lane>>4)*8+j.
__device__ __forceinline__ bf8 read_frag(const unsigned short* lds, int row, int kk, int lane) {
    int byte = kk * 64 + ((lane >> 4) << 4);
    int off  = row * 128 + swz16(row, byte);
    return *reinterpret_cast<const bf8*>(reinterpret_cast<const char*>(lds) + off);
}

// ---------------- Kernel 0: Q fp32 -> bf16 once ----------------
__global__ __launch_bounds__(256) void k_qprep(const float* __restrict__ Q,
                                               unsigned short* __restrict__ Qbf) {
    int i = blockIdx.x * 256 + threadIdx.x;          // T*D/4 = 65536 float4s
    float4 f = reinterpret_cast<const float4*>(Q)[i];
    ushort4 u;
    u.x = f2bf(f.x); u.y = f2bf(f.y); u.z = f2bf(f.z); u.w = f2bf(f.w);
    reinterpret_cast<ushort4*>(Qbf)[i] = u;
}

// ==================== Kernel 1: scores = Q . mask^T / 64 ====================
// grid (L/64, B) = 256 blocks, 1/CU. Tile 64(T) x 64(l), K-step 64.
// K-loop start phased per block (circular): decorrelates address bits [8:13]
// across blocks so HBM channel load stays uniform.
__global__ __launch_bounds__(256, 1) void k_scores(
    const float* __restrict__ mask, const unsigned short* __restrict__ Qbf,
    float* __restrict__ scores) {
    __shared__ unsigned short lA[2][64 * 64];   // Q tile   [t][k] bf16
    __shared__ unsigned short lB[2][64 * 64];   // mask tile[l][k] bf16
    const int tid  = threadIdx.x;
    const int lane = tid & 63;
    const int wave = tid >> 6;
    const int wm = wave >> 1, wn = wave & 1;     // 2x2 waves, 32x32 out each
    const int b  = blockIdx.y;
    const int l0 = blockIdx.x * 64;
    const float* __restrict__ Mb = mask + (size_t)b * L_ * D_;

    f32x4 acc[2][2] = {};
    uint4  ra[2];    // Q slab:   64x64 bf16 = 8 KB  -> 2 uint4/thread
    float4 rb[4];    // mask slab:64x64 f32  = 16 KB -> 4 float4/thread

    const int NT    = D_ / 64;                   // 64 k-chunks
    const int phase = blockIdx.x & (NT - 1);     // full coverage of k-chunk positions
    auto kof = [&](int kt) { int k = kt + phase; if (k >= NT) k -= NT; return k * 64; };

    auto loadTiles = [&](int k0) {
#pragma unroll
        for (int s = 0; s < 2; ++s) {
            int slot = tid + s * 256;            // 512 slots: 64 rows x 8 chunks
            int r = slot >> 3, c = slot & 7;
            ra[s] = *reinterpret_cast<const uint4*>(Qbf + (size_t)r * D_ + k0 + c * 8);
        }
#pragma unroll
        for (int s = 0; s < 4; ++s) {
            int slot = tid + s * 256;            // 1024 slots: 64 rows x 16 float4
            int r = slot >> 4, c = slot & 15;
            rb[s] = *reinterpret_cast<const float4*>(Mb + (size_t)(l0 + r) * D_ + k0 + c * 4);
        }
    };
    auto writeTiles = [&](int buf) {
#pragma unroll
        for (int s = 0; s < 2; ++s) {
            int slot = tid + s * 256;
            int r = slot >> 3, c = slot & 7;
            int off = r * 128 + swz16(r, c * 16);
            *reinterpret_cast<uint4*>(reinterpret_cast<char*>(lA[buf]) + off) = ra[s];
        }
#pragma unroll
        for (int s = 0; s < 4; ++s) {
            int slot = tid + s * 256;
            int r = slot >> 4, c = slot & 15;
            int off = r * 128 + swz16(r, c * 8);
            ushort4 u;
            u.x = f2bf(rb[s].x); u.y = f2bf(rb[s].y); u.z = f2bf(rb[s].z); u.w = f2bf(rb[s].w);
            *reinterpret_cast<ushort4*>(reinterpret_cast<char*>(lB[buf]) + off) = u;
        }
    };

    loadTiles(kof(0));
    writeTiles(0);
    __syncthreads();
    for (int kt = 0; kt < NT; ++kt) {
        int cur = kt & 1;
        if (kt + 1 < NT) loadTiles(kof(kt + 1));  // issue next-tile global loads early
#pragma unroll
        for (int kk = 0; kk < 2; ++kk) {
            bf8 a0 = read_frag(lA[cur], wm * 32 +      (lane & 15), kk, lane);
            bf8 a1 = read_frag(lA[cur], wm * 32 + 16 + (lane & 15), kk, lane);
            bf8 b0 = read_frag(lB[cur], wn * 32 +      (lane & 15), kk, lane);
            bf8 b1 = read_frag(lB[cur], wn * 32 + 16 + (lane & 15), kk, lane);
            acc[0][0] = __builtin_amdgcn_mfma_f32_16x16x32_bf16(a0, b0, acc[0][0], 0, 0, 0);
            acc[0][1] = __builtin_amdgcn_mfma_f32_16x16x32_bf16(a0, b1, acc[0][1], 0, 0, 0);
            acc[1][0] = __builtin_amdgcn_mfma_f32_16x16x32_bf16(a1, b0, acc[1][0], 0, 0, 0);
            acc[1][1] = __builtin_amdgcn_mfma_f32_16x16x32_bf16(a1, b1, acc[1][1], 0, 0, 0);
        }
        if (kt + 1 < NT) writeTiles(cur ^ 1);     // vmcnt waits here, overlapped with MFMA
        __syncthreads();
    }

    // C/D layout: col = lane&15, row = (lane>>4)*4 + reg  (m89-verified)
    const int rgrp = (lane >> 4) * 4;
    const int cidx = lane & 15;
#pragma unroll
    for (int mi = 0; mi < 2; ++mi)
#pragma unroll
        for (int nj = 0; nj < 2; ++nj)
#pragma unroll
            for (int r = 0; r < 4; ++r) {
                int t = wm * 32 + mi * 16 + rgrp + r;
                int l = l0 + wn * 32 + nj * 16 + cidx;
                scores[((size_t)b * T_ + t) * L_ + l] = acc[mi][nj][r] * 0.015625f; // 1/sqrt(4096)
            }
}

// ---------------- Kernel 2: masked softmax over L, fp32 scores -> bf16 attn ----------------
__global__ __launch_bounds__(256, 4) void k_softmax(
    const float* __restrict__ scores, const int* __restrict__ am,
    unsigned short* __restrict__ attn) {
    const int row  = blockIdx.x;                 // b*T + t
    const int tid  = threadIdx.x;
    const int lane = tid & 63;
    const int wave = tid >> 6;
    const float* __restrict__ s = scores + (size_t)row * L_;
    const int*   __restrict__ m = am     + (size_t)row * L_;
    __shared__ float redmax[4], redsum[4];

    float v[16];
#pragma unroll
    for (int j = 0; j < 4; ++j) {
        float4 f = *(reinterpret_cast<const float4*>(s) + tid + j * 256);
        int4   q = *(reinterpret_cast<const int4*>(m)   + tid + j * 256);
        v[j * 4 + 0] = q.x ? -1.0e9f : f.x;
        v[j * 4 + 1] = q.y ? -1.0e9f : f.y;
        v[j * 4 + 2] = q.z ? -1.0e9f : f.z;
        v[j * 4 + 3] = q.w ? -1.0e9f : f.w;
    }
    float mx = -3.0e38f;
#pragma unroll
    for (int i = 0; i < 16; ++i) mx = fmaxf(mx, v[i]);
#pragma unroll
    for (int off = 32; off; off >>= 1) mx = fmaxf(mx, __shfl_xor(mx, off, 64));
    if (lane == 0) redmax[wave] = mx;
    __syncthreads();
    mx = fmaxf(fmaxf(redmax[0], redmax[1]), fmaxf(redmax[2], redmax[3]));

    float z = 0.f;
#pragma unroll
    for (int i = 0; i < 16; ++i) {
        v[i] = exp2f((v[i] - mx) * 1.4426950408889634f);
        z += v[i];
    }
#pragma unroll
    for (int off = 32; off; off >>= 1) z += __shfl_xor(z, off, 64);
    if (lane == 0) redsum[wave] = z;
    __syncthreads();
    z = (redsum[0] + redsum[1]) + (redsum[2] + redsum[3]);
    float inv = 1.0f / z;

    unsigned short* __restrict__ arow = attn + (size_t)row * L_;
#pragma unroll
    for (int j = 0; j < 4; ++j) {
        ushort4 u;
        u.x = f2bf(v[j * 4 + 0] * inv);
        u.y = f2bf(v[j * 4 + 1] * inv);
        u.z = f2bf(v[j * 4 + 2] * inv);
        u.w = f2bf(v[j * 4 + 3] * inv);
        *(reinterpret_cast<ushort4*>(arow) + tid + j * 256) = u;
    }
}

// ==================== Kernel 3: context = attn @ mask ====================
// grid (D/64, B) = 256 blocks, 1/CU. Tile 64(T) x 64(d), K(=l)-step 64, phased.
// mask tile staged TRANSPOSED into LDS as [d][l] bf16.
__global__ __launch_bounds__(256, 1) void k_context(
    const float* __restrict__ mask, const unsigned short* __restrict__ attn,
    float* __restrict__ out) {
    __shared__ unsigned short lA[2][64 * 64];   // attn [t][l]
    __shared__ unsigned short lB[2][64 * 64];   // mask [d][l] (transposed)
    const int tid  = threadIdx.x;
    const int lane = tid & 63;
    const int wave = tid >> 6;
    const int wm = wave >> 1, wn = wave & 1;
    const int b  = blockIdx.y;
    const int d0 = blockIdx.x * 64;
    const float*          __restrict__ Mb = mask + (size_t)b * L_ * D_;
    const unsigned short* __restrict__ Ab = attn + (size_t)b * T_ * L_;

    f32x4 acc[2][2] = {};
    uint4  ra[2];    // attn slab: 64 t x 64 l bf16 = 8 KB
    float4 rb[4];    // mask slab: 64 l x 64 d f32  = 16 KB

    const int NT    = L_ / 64;                   // 64 l-chunks
    const int phase = blockIdx.x & (NT - 1);
    auto kof = [&](int kt) { int k = kt + phase; if (k >= NT) k -= NT; return k * 64; };

    auto loadTiles = [&](int k0) {
#pragma unroll
        for (int s = 0; s < 2; ++s) {
            int slot = tid + s * 256;            // 64 t-rows x 8 chunks
            int r = slot >> 3, c = slot & 7;
            ra[s] = *reinterpret_cast<const uint4*>(Ab + (size_t)r * L_ + k0 + c * 8);
        }
#pragma unroll
        for (int s = 0; s < 4; ++s) {
            int slot = tid + s * 256;            // 64 l-rows x 16 float4
            int kl = slot >> 4, c = slot & 15;
            rb[s] = *reinterpret_cast<const float4*>(Mb + (size_t)(k0 + kl) * D_ + d0 + c * 4);
        }
    };
    auto writeTiles = [&](int buf) {
#pragma unroll
        for (int s = 0; s < 2; ++s) {
            int slot = tid + s * 256;
            int r = slot >> 3, c = slot & 7;
            int off = r * 128 + swz16(r, c * 16);
            *reinterpret_cast<uint4*>(reinterpret_cast<char*>(lA[buf]) + off) = ra[s];
        }
#pragma unroll
        for (int s = 0; s < 4; ++s) {
            int slot = tid + s * 256;
            int kl = slot >> 4, c = slot & 15;
            float fv[4] = { rb[s].x, rb[s].y, rb[s].z, rb[s].w };
#pragma unroll
            for (int i = 0; i < 4; ++i) {
                int d = c * 4 + i;
                int off = d * 128 + swz16(d, kl * 2);   // transposed scalar b16 store
                *reinterpret_cast<unsigned short*>(reinterpret_cast<char*>(lB[buf]) + off) = f2bf(fv[i]);
            }
        }
    };

    loadTiles(kof(0));
    writeTiles(0);
    __syncthreads();
    for (int kt = 0; kt < NT; ++kt) {
        int cur = kt & 1;
        if (kt + 1 < NT) loadTiles(kof(kt + 1));
#pragma unroll
        for (int kk = 0; kk < 2; ++kk) {
            bf8 a0 = read_frag(lA[cur], wm * 32 +      (lane & 15), kk, lane);
            bf8 a1 = read_frag(lA[cur], wm * 32 + 16 + (lane & 15), kk, lane);
            bf8 b0 = read_frag(lB[cur], wn * 32 +      (lane & 15), kk, lane);
            bf8 b1 = read_frag(lB[cur], wn * 32 + 16 + (lane & 15), kk, lane);
            acc[0][0] = __builtin_amdgcn_mfma_f32_16x16x32_bf16(a0, b0, acc[0][0], 0, 0, 0);
            acc[0][1] = __builtin_amdgcn_mfma_f32_16x16x32_bf16(a0, b1, acc[0][1], 0, 0, 0);
            acc[1][0] = __builtin_amdgcn_mfma_f32_16x16x32_bf16(a1, b0, acc[1][0], 0, 0, 0);
            acc[1][1] = __builtin_amdgcn_mfma_f32_16x16x32_bf16(a1, b1, acc[1][1], 0, 0, 0);
        }
        if (kt + 1 < NT) writeTiles(cur ^ 1);
        __syncthreads();
    }

    const int rgrp = (lane >> 4) * 4;
    const int cidx = lane & 15;
#pragma unroll
    for (int mi = 0; mi < 2; ++mi)
#pragma unroll
        for (int nj = 0; nj < 2; ++nj)
#pragma unroll
            for (int r = 0; r < 4; ++r) {
                int t = wm * 32 + mi * 16 + rgrp + r;
                int d = d0 + wn * 32 + nj * 16 + cidx;
                out[((size_t)b * T_ + t) * D_ + d] = acc[mi][nj][r];
            }
}

extern "C" void kernel_launch(void* const* d_in, const int* in_sizes, int n_in,
                              void* d_out, int out_size, void* d_ws, size_t ws_size,
                              hipStream_t stream) {
    const float* mask = (const float*)d_in[0];        // [B, L, D] fp32
    const float* Q    = (const float*)d_in[1];        // [1, T, D] fp32
    const int*   am   = (const int*)d_in[2];          // [B, T, L] int (bool)
    float* out = (float*)d_out;                       // [B, T, D] fp32

    unsigned short* attn = (unsigned short*)d_ws;                                     // 2 MB bf16
    unsigned short* Qbf  = (unsigned short*)((char*)d_ws + (size_t)B_ * T_ * L_ * 2); // 512 KB

    k_qprep<<<dim3(T_ * D_ / 4 / 256), 256, 0, stream>>>(Q, Qbf);
    k_scores<<<dim3(L_ / 64, B_), 256, 0, stream>>>(mask, Qbf, out);
    k_softmax<<<dim3(B_ * T_), 256, 0, stream>>>(out, am, attn);
    k_context<<<dim3(D_ / 64, B_), 256, 0, stream>>>(mask, attn, out);
}